// Round 4
// baseline (204.688 us; speedup 1.0000x reference)
//
#include <hip/hip_runtime.h>
#include <cstdint>

#define HEADS 4
#define DD    32
#define HD    128     // HEADS*DD
#define SCOL  32      // padded score columns (20 used)
#define NEGS  0.2f

typedef __attribute__((ext_vector_type(8))) short bf16x8;
typedef __attribute__((ext_vector_type(4))) float f32x4;

__device__ __forceinline__ float bl(unsigned u) { return __uint_as_float(u << 16); }
__device__ __forceinline__ float bh(unsigned u) { return __uint_as_float(u & 0xffff0000u); }
__device__ __forceinline__ unsigned short f2b(float f) {
    unsigned u = __float_as_uint(f);
    u += 0x7fffu + ((u >> 16) & 1u);   // RNE (finite inputs only)
    return (unsigned short)(u >> 16);
}

// ---------- K0: fold attn_l/attn_r/edge-embed through Wq/Wk into C (128 x 32) fp32
// cols 0..3: Wq@attn_l[h] (score_src) | 4..7: Wk@attn_r[h] (score_dst)
// cols 8..19: Wq@ee[t,h] (qee, t*4+h)  | 20..31: zero pad
__global__ void k_buildC(const float* __restrict__ Wq, const float* __restrict__ Wk,
                         const float* __restrict__ attn, const float* __restrict__ ee,
                         float* __restrict__ C) {
    int tid = blockIdx.x*blockDim.x + threadIdx.x;
    if (tid >= HD*SCOL) return;
    int i = tid >> 5, c = tid & 31;
    float s = 0.f;
    if (c < 8) {
        int h = c & 3;
        const float* w = ((c < 4) ? Wq : Wk) + i*HD + h*DD;
        const float* a = attn + h*64 + ((c < 4) ? 0 : DD);
        #pragma unroll
        for (int d = 0; d < DD; ++d) s += w[d]*a[d];
    } else if (c < 20) {
        int idx = c - 8; int ty = idx >> 2; int h = idx & 3;
        const float* w  = Wq + i*HD + h*DD;
        const float* em = ee + ty*HD + h*DD;
        #pragma unroll
        for (int d = 0; d < DD; ++d) s += w[d]*em[d];
    }
    C[i*SCOL + c] = s;
}

// ---------- pack Wcat=[Wv | C] (128x160) and Wo (128x128) into bf16 MFMA B-fragment order
// Bp[(ctile*4+kk)*64 + lane][j] = B[kk*32 + (lane>>4)*8 + j][ctile*16 + (lane&15)]
__global__ void k_pack(const float* __restrict__ Wv, const float* __restrict__ C,
                       const float* __restrict__ Wo,
                       unsigned short* __restrict__ Bpv, unsigned short* __restrict__ Bpo) {
    int id = blockIdx.x*256 + threadIdx.x;
    if (id < 20480) {                      // 10 ctiles * 4 kk * 64 lanes * 8
        int j = id & 7, l = (id >> 3) & 63, tk = id >> 9;
        int t = tk >> 2, kk = tk & 3;
        int k = kk*32 + (l >> 4)*8 + j;
        int n = t*16 + (l & 15);
        float val = (n < HD) ? Wv[k*HD + n] : C[k*SCOL + (n - HD)];
        Bpv[id] = f2b(val);
    } else if (id < 36864) {               // 8 ctiles * 4 kk * 64 * 8
        int o = id - 20480;
        int j = o & 7, l = (o >> 3) & 63, tk = o >> 9;
        int t = tk >> 2, kk = tk & 3;
        int k = kk*32 + (l >> 4)*8 + j;
        int n = t*16 + (l & 15);
        Bpo[o] = f2b(Wo[k*HD + n]);
    }
}

// ---------- K1: MFMA: [v | scores] = bf16(x) @ [Wv | C]   (64 nodes/block, 4 waves)
// v written bf16, scores fp32.
__global__ __launch_bounds__(256)
void k_vproj(const float* __restrict__ x, const unsigned short* __restrict__ Bpv,
             unsigned short* __restrict__ vbf, float* __restrict__ scores, int N) {
    __shared__ unsigned short xs[64*136];  // row stride 272B (pad: rotates banks by 4/row)
    const int t = threadIdx.x;
    const int nbase = blockIdx.x * 64;
    const float4* xg = (const float4*)x;
    #pragma unroll
    for (int k = 0; k < 8; ++k) {
        int fi = t + k*256;                // float4 index within 64x32-float4 tile
        int row = fi >> 5, c4 = fi & 31;
        int node = nbase + row;
        float4 val = make_float4(0.f,0.f,0.f,0.f);
        if (node < N) val = xg[(size_t)nbase*32 + fi];
        unsigned short p[4] = { f2b(val.x), f2b(val.y), f2b(val.z), f2b(val.w) };
        *(uint2*)((char*)xs + row*272 + c4*8) = *(const uint2*)p;
    }
    __syncthreads();
    const int wid = t >> 6, l = t & 63;
    const int lr = l & 15, lg = l >> 4;
    bf16x8 a[4];
    #pragma unroll
    for (int kk = 0; kk < 4; ++kk)
        a[kk] = *(const bf16x8*)((const char*)xs + (16*wid + lr)*272 + kk*64 + lg*16);
    const bf16x8* Bp = (const bf16x8*)Bpv;
    #pragma unroll
    for (int ct = 0; ct < 10; ++ct) {
        f32x4 acc = {0.f, 0.f, 0.f, 0.f};
        #pragma unroll
        for (int kk = 0; kk < 4; ++kk)
            acc = __builtin_amdgcn_mfma_f32_16x16x32_bf16(a[kk], Bp[(ct*4 + kk)*64 + l], acc, 0, 0, 0);
        if (ct < 8) {
            int col = ct*16 + lr;
            #pragma unroll
            for (int r = 0; r < 4; ++r) {
                int node = nbase + 16*wid + lg*4 + r;
                if (node < N) vbf[(size_t)node*HD + col] = f2b(acc[r]);
            }
        } else {
            int col = (ct - 8)*16 + lr;
            #pragma unroll
            for (int r = 0; r < 4; ++r) {
                int node = nbase + 16*wid + lg*4 + r;
                if (node < N) scores[(size_t)node*SCOL + col] = acc[r];
            }
        }
    }
}

// ---------- degree histogram
__global__ void k_count(const int* __restrict__ ei, int* __restrict__ counts, int E) {
    int e = blockIdx.x*256 + threadIdx.x;
    if (e < E) atomicAdd(&counts[ei[E + e]], 1);
}

// ---------- exclusive scan (3 kernels), chunk = 2048
__global__ __launch_bounds__(256)
void k_scan1(const int* __restrict__ counts, int* __restrict__ off,
             int* __restrict__ bsum, int N) {
    __shared__ int sh[256];
    int t = threadIdx.x;
    int base = blockIdx.x*2048 + t*8;
    int vals[8]; int s = 0;
    #pragma unroll
    for (int k = 0; k < 8; ++k) {
        int idx = base + k;
        int cv = (idx < N) ? counts[idx] : 0;
        s += cv; vals[k] = s;
    }
    sh[t] = s;
    __syncthreads();
    for (int o = 1; o < 256; o <<= 1) {
        int v2 = (t >= o) ? sh[t-o] : 0;
        __syncthreads();
        sh[t] += v2;
        __syncthreads();
    }
    int excl = (t > 0) ? sh[t-1] : 0;
    #pragma unroll
    for (int k = 0; k < 8; ++k) {
        int idx = base + k;
        if (idx < N) off[idx+1] = excl + vals[k];
    }
    if (t == 255) bsum[blockIdx.x] = sh[255];
    if (blockIdx.x == 0 && t == 0) off[0] = 0;
}
__global__ void k_scan2(int* __restrict__ bsum, int nb) {
    __shared__ int sh[256];
    int t = threadIdx.x;
    sh[t] = (t < nb) ? bsum[t] : 0;
    __syncthreads();
    for (int o = 1; o < 256; o <<= 1) {
        int v2 = (t >= o) ? sh[t-o] : 0;
        __syncthreads();
        sh[t] += v2;
        __syncthreads();
    }
    if (t < nb) bsum[t] = (t > 0) ? sh[t-1] : 0;
}
__global__ void k_scan3(int* __restrict__ off, const int* __restrict__ bsum, int N) {
    int i = blockIdx.x*256 + threadIdx.x;
    if (i < N) off[i+1] += bsum[i >> 11];
}

// ---------- slot assignment only: scatter packed (src | ty<<20), 4B per edge.
// w = exp(s) is recomputed in k_agg from the L2/L3-resident scores rows.
__global__ void k_slot(const int* __restrict__ ei, const int* __restrict__ et,
                       int* __restrict__ off, unsigned* __restrict__ pk, int E) {
    int e = blockIdx.x*256 + threadIdx.x;
    if (e >= E) return;
    int src = ei[e], dst = ei[E + e], ty = et[e];
    int slot = atomicAdd(&off[dst], 1);
    pk[slot] = (unsigned)src | ((unsigned)ty << 20);
}

// ---------- aggregation: one wave/node, 8 edge-groups x 8 dim-lanes (16 dims/lane)
// per edge: s = leaky(score_src[src]+score_dst[dst]) + qee[src][ty]; w = exp(s)
// z = sum(w), acc = sum(w * v[src]); out = acc/(z+1e-6)
// (max-subtraction: only effect is 1e-6 epsilon scaling, |da|~1e-7;
//  min(a,1) and clip(+-50) provably dead -> aggregation is linear.)
__global__ __launch_bounds__(256)
void k_agg(const int* __restrict__ off, const unsigned* __restrict__ pk,
           const float* __restrict__ scores, const unsigned short* __restrict__ vbf,
           unsigned short* __restrict__ outbf, int N) {
    const int wid  = threadIdx.x >> 6;
    const int lane = threadIdx.x & 63;
    const int n = blockIdx.x*4 + wid;
    if (n >= N) return;
    const int start = (n > 0) ? off[n-1] : 0;   // k_slot advanced off[n] to seg end
    const int end   = off[n];
    const int g  = lane >> 3;                   // edge group 0..7
    const int dl = lane & 7;                    // dims dl*16 .. dl*16+15
    const int hh = dl >> 1;                     // head of this lane's dims
    const float sd = scores[(size_t)n*SCOL + 4 + hh];   // score_dst[n][hh], once per node
    float z = 0.f;
    float c[16];
    #pragma unroll
    for (int i = 0; i < 16; ++i) c[i] = 0.f;

    int  sl0 = start + g;
    bool p0 = sl0 < end;
    float f0 = 0.f, q0 = 0.f;
    uint4 va0 = make_uint4(0,0,0,0), vb0 = make_uint4(0,0,0,0);
    if (p0) {
        unsigned pe = pk[sl0];
        int s = pe & 0xFFFFF, ty = pe >> 20;
        const float* ps = scores + (size_t)s*SCOL;
        f0 = ps[hh]; q0 = ps[8 + 4*ty + hh];
        const unsigned short* pv = vbf + (size_t)s*HD + dl*16;
        va0 = *(const uint4*)pv; vb0 = *(const uint4*)(pv + 8);
    }
    while (p0) {
        int  sl1 = sl0 + 8;
        bool p1 = sl1 < end;
        float f1 = 0.f, q1 = 0.f;
        uint4 va1 = make_uint4(0,0,0,0), vb1 = make_uint4(0,0,0,0);
        if (p1) {
            unsigned pe = pk[sl1];
            int s = pe & 0xFFFFF, ty = pe >> 20;
            const float* ps = scores + (size_t)s*SCOL;
            f1 = ps[hh]; q1 = ps[8 + 4*ty + hh];
            const unsigned short* pv = vbf + (size_t)s*HD + dl*16;
            va1 = *(const uint4*)pv; vb1 = *(const uint4*)(pv + 8);
        }
        float t = f0 + sd;
        float w = __expf(((t >= 0.f) ? t : NEGS*t) + q0);
        z += w;
        c[0] += w*bl(va0.x); c[1] += w*bh(va0.x);
        c[2] += w*bl(va0.y); c[3] += w*bh(va0.y);
        c[4] += w*bl(va0.z); c[5] += w*bh(va0.z);
        c[6] += w*bl(va0.w); c[7] += w*bh(va0.w);
        c[8] += w*bl(vb0.x); c[9] += w*bh(vb0.x);
        c[10]+= w*bl(vb0.y); c[11]+= w*bh(vb0.y);
        c[12]+= w*bl(vb0.z); c[13]+= w*bh(vb0.z);
        c[14]+= w*bl(vb0.w); c[15]+= w*bh(vb0.w);
        sl0 = sl1; p0 = p1; f0 = f1; q0 = q1; va0 = va1; vb0 = vb1;
    }
    #pragma unroll
    for (int o = 8; o <= 32; o <<= 1) {
        z += __shfl_xor(z, o);
        #pragma unroll
        for (int i = 0; i < 16; ++i) c[i] += __shfl_xor(c[i], o);
    }
    if (g == 0) {
        float r = 1.f/(z + 1e-6f);
        unsigned short pbuf[16];
        #pragma unroll
        for (int i = 0; i < 16; ++i) pbuf[i] = f2b(c[i]*r);
        unsigned short* po = outbf + (size_t)n*HD + dl*16;
        *(uint4*)po       = *(const uint4*)pbuf;
        *(uint4*)(po + 8) = *(const uint4*)(pbuf + 8);
    }
}

// ---------- output GEMM (MFMA): out = bf16(outacc) @ Wo + bo, no LDS
__global__ __launch_bounds__(256)
void k_out(const unsigned short* __restrict__ accbf, const unsigned short* __restrict__ Bpo,
           const float* __restrict__ bo, float* __restrict__ out, int N) {
    const int t = threadIdx.x;
    const int wid = t >> 6, l = t & 63;
    const int tile = blockIdx.x*4 + wid;
    if (tile*16 >= N) return;
    const int lr = l & 15, lg = l >> 4;
    const int r0 = tile*16;
    bf16x8 a[4];
    #pragma unroll
    for (int kk = 0; kk < 4; ++kk)
        a[kk] = *(const bf16x8*)&accbf[(size_t)(r0 + lr)*HD + kk*32 + lg*8];
    const bf16x8* Bp = (const bf16x8*)Bpo;
    #pragma unroll
    for (int ct = 0; ct < 8; ++ct) {
        f32x4 acc = {0.f, 0.f, 0.f, 0.f};
        #pragma unroll
        for (int kk = 0; kk < 4; ++kk)
            acc = __builtin_amdgcn_mfma_f32_16x16x32_bf16(a[kk], Bp[(ct*4 + kk)*64 + l], acc, 0, 0, 0);
        int col = ct*16 + lr;
        float bias = bo[col];
        #pragma unroll
        for (int r = 0; r < 4; ++r) {
            int node = r0 + lg*4 + r;
            if (node < N) out[(size_t)node*HD + col] = acc[r] + bias;
        }
    }
}

extern "C" void kernel_launch(void* const* d_in, const int* in_sizes, int n_in,
                              void* d_out, int out_size, void* d_ws, size_t ws_size,
                              hipStream_t stream) {
    const float* x    = (const float*)d_in[0];
    const int*   ei   = (const int*)  d_in[1];
    const int*   et   = (const int*)  d_in[2];
    const float* Wq   = (const float*)d_in[3];
    const float* Wk   = (const float*)d_in[4];
    const float* Wv   = (const float*)d_in[5];
    const float* attn = (const float*)d_in[6];
    const float* ee   = (const float*)d_in[7];
    const float* Wo   = (const float*)d_in[8];
    const float* bo   = (const float*)d_in[9];
    float* out = (float*)d_out;
    const int N = in_sizes[0] / HD;
    const int E = in_sizes[2];

    char* w = (char*)d_ws;
    auto alloc = [&](size_t bytes) -> void* {
        void* p = (void*)w;
        w += (bytes + 255) & ~(size_t)255;
        return p;
    };
    float*          C      = (float*)         alloc((size_t)HD*SCOL*sizeof(float));
    unsigned short* Bpv    = (unsigned short*)alloc((size_t)20480*sizeof(unsigned short));
    unsigned short* Bpo    = (unsigned short*)alloc((size_t)16384*sizeof(unsigned short));
    unsigned short* vbf    = (unsigned short*)alloc((size_t)N*HD*sizeof(unsigned short));
    float*          scores = (float*)         alloc((size_t)N*SCOL*sizeof(float));
    int*            counts = (int*)           alloc((size_t)N*sizeof(int));
    int*            off    = (int*)           alloc((size_t)(N+1)*sizeof(int));
    int*            bsum   = (int*)           alloc(4096);
    unsigned*       pk     = (unsigned*)      alloc((size_t)E*sizeof(unsigned));
    unsigned short* outbf  = (unsigned short*)alloc((size_t)N*HD*sizeof(unsigned short));

    hipMemsetAsync(counts, 0, (size_t)N*sizeof(int), stream);
    k_buildC<<<(HD*SCOL + 255)/256, 256, 0, stream>>>(Wq, Wk, attn, ee, C);
    k_pack<<<144, 256, 0, stream>>>(Wv, C, Wo, Bpv, Bpo);
    k_vproj<<<(N + 63)/64, 256, 0, stream>>>(x, Bpv, vbf, scores, N);
    k_count<<<(E + 255)/256, 256, 0, stream>>>(ei, counts, E);
    const int nb = (N + 2047)/2048;
    k_scan1<<<nb, 256, 0, stream>>>(counts, off, bsum, N);
    k_scan2<<<1, 256, 0, stream>>>(bsum, nb);
    k_scan3<<<(N + 255)/256, 256, 0, stream>>>(off, bsum, N);
    k_slot<<<(E + 255)/256, 256, 0, stream>>>(ei, et, off, pk, E);
    k_agg<<<(N + 3)/4, 256, 0, stream>>>(off, pk, scores, vbf, outbf, N);
    k_out<<<(N + 63)/64, 256, 0, stream>>>(outbf, Bpo, bo, out, N);
}